// Round 5
// baseline (490.295 us; speedup 1.0000x reference)
//
#include <hip/hip_runtime.h>
#include <hip/hip_bf16.h>
#include <math.h>

#define N_ENT 200000
#define DD 256
#define NB 64
#define NK 21
#define PROJ 200
#define NS 5
#define NQ 1024
#define PADID (N_ENT - 1)
#define LOGMIN -69.07755279f

typedef short s16x8 __attribute__((ext_vector_type(8)));
typedef float f32x4 __attribute__((ext_vector_type(4)));

__device__ inline unsigned short f2bf(float x) {
  __hip_bfloat16 h = __float2bfloat16(x);
  return __builtin_bit_cast(unsigned short, h);
}

// ---------------- K0: wT[j][d] = attn_w[d][j]
__global__ __launch_bounds__(256) void k_transpose(const float* __restrict__ w,
                                                   float* __restrict__ wT) {
  int j = blockIdx.x, d = threadIdx.x;
  wT[j * DD + d] = w[d * DD + j];
}

// ---------------- K3: per-support: t2 inline + Bb[m][k] (bf16) = l2norm(rel[s_nb]) * s_att
__global__ __launch_bounds__(256) void k_support(const int* __restrict__ sh, const int* __restrict__ st,
                                                 const int* __restrict__ ed,
                                                 const float* __restrict__ ent, const float* __restrict__ rel,
                                                 const float* __restrict__ wT, const float* __restrict__ ab,
                                                 unsigned short* __restrict__ Bb) {
  int s = blockIdx.x, tid = threadIdx.x;
  __shared__ float tv[DD], t2s[DD];
  __shared__ int nbs[NB];
  __shared__ float att[NB];
  int head = sh[s], tail = st[s];
  if (tid < NB) nbs[tid] = ed[((size_t)tail * NB + tid) * 2 + 1];
  tv[tid] = ent[(size_t)tail * DD + tid] - ent[(size_t)head * DD + tid];
  __syncthreads();
  float acc0 = ab[tid];
  #pragma unroll 8
  for (int j = 0; j < DD; ++j) acc0 = fmaf(tv[j], wT[j * DD + tid], acc0);
  t2s[tid] = acc0;
  __syncthreads();
  int n = tid >> 2, seg = tid & 3;
  const float4* er = (const float4*)(ent + (size_t)nbs[n] * DD + seg * 64);
  const float4* ts = (const float4*)(t2s + seg * 64);
  float a = 0.f;
  #pragma unroll
  for (int j = 0; j < 16; ++j) {
    float4 v = er[j], t = ts[j];
    a += v.x * t.x + v.y * t.y + v.z * t.z + v.w * t.w;
  }
  a += __shfl_xor(a, 1);
  a += __shfl_xor(a, 2);
  if (seg == 0) att[n] = a;
  const float4* rr = (const float4*)(rel + (size_t)nbs[n] * DD + seg * 64);
  float4 buf[16];
  float ss = 0.f;
  #pragma unroll
  for (int j = 0; j < 16; ++j) {
    float4 v = rr[j]; buf[j] = v;
    ss += v.x * v.x + v.y * v.y + v.z * v.z + v.w * v.w;
  }
  ss += __shfl_xor(ss, 1);
  ss += __shfl_xor(ss, 2);
  __syncthreads();
  float scale = att[n] / fmaxf(sqrtf(ss), 1e-12f);
  unsigned short* ob = Bb + ((size_t)s * NB + n) * DD + seg * 64;
  #pragma unroll
  for (int j = 0; j < 16; ++j) {
    float4 v = buf[j];
    ob[j * 4 + 0] = f2bf(v.x * scale);
    ob[j * 4 + 1] = f2bf(v.y * scale);
    ob[j * 4 + 2] = f2bf(v.z * scale);
    ob[j * 4 + 3] = f2bf(v.w * scale);
  }
}

// ---------------- K4: fully fused per-q: t2 + q_att + MFMA GEMM + pool + KDE + MLP + max_s
// A [64][256] bf16 LDS (stride 264); B [320][256] bf16 global (L2-resident, zero-barrier GEMM).
#define AP 264
__global__ __launch_bounds__(256) void k_all(
    const int* __restrict__ qh, const int* __restrict__ qt, const int* __restrict__ ed,
    const float* __restrict__ ent, const float* __restrict__ rel,
    const float* __restrict__ wT, const float* __restrict__ ab,
    const unsigned short* __restrict__ Bg,
    const float* __restrict__ d1w, const float* __restrict__ d1b,
    const float* __restrict__ d2w, const float* __restrict__ d2b,
    float* __restrict__ out) {
  int q = blockIdx.x, tid = threadIdx.x;
  int wv = tid >> 6, ln = tid & 63;
  int fr = ln & 15, kb = ln >> 4;

  __shared__ float tv[DD], t2s[DD];
  __shared__ __align__(16) unsigned short As[NB * AP];   // 33,792 B
  __shared__ float pmax[NS][4][NB], pmin[NS][4][NB];     // 10,240 B
  __shared__ float att[NB], msk[NB], pol[NB], te[NK + 3], wred[4];
  __shared__ int nbs[NB];
  // ~47 KB LDS -> 3 blocks/CU

  int head = qh[q], tail = qt[q];
  if (tid < NB) {
    int nb = ed[((size_t)tail * NB + tid) * 2 + 1];
    nbs[tid] = nb;
    msk[tid] = (nb != PADID) ? 0.01f : 0.0f;
  }
  tv[tid] = ent[(size_t)tail * DD + tid] - ent[(size_t)head * DD + tid];
  __syncthreads();

  int n = tid >> 2, seg = tid & 3;
  // --- issue rel gather EARLY (latency hides under the t2 matvec below)
  const float4* rr = (const float4*)(rel + (size_t)nbs[n] * DD + seg * 64);
  float4 buf[16];
  #pragma unroll
  for (int j = 0; j < 16; ++j) buf[j] = rr[j];

  // --- t2 matvec: t2[d] = ab[d] + sum_j tv[j] * wT[j][d]
  float acc0 = ab[tid];
  #pragma unroll 8
  for (int j = 0; j < DD; ++j) acc0 = fmaf(tv[j], wT[j * DD + tid], acc0);
  t2s[tid] = acc0;

  // --- l2norm rel rows -> bf16 LDS A
  {
    float ss = 0.f;
    #pragma unroll
    for (int j = 0; j < 16; ++j) {
      float4 v = buf[j];
      ss += v.x * v.x + v.y * v.y + v.z * v.z + v.w * v.w;
    }
    ss += __shfl_xor(ss, 1);
    ss += __shfl_xor(ss, 2);
    float inv = 1.0f / fmaxf(sqrtf(ss), 1e-12f);
    unsigned short* ap = As + n * AP + seg * 64;
    #pragma unroll
    for (int j = 0; j < 16; ++j) {
      float4 v = buf[j];
      unsigned int lo = (unsigned int)f2bf(v.x * inv) | ((unsigned int)f2bf(v.y * inv) << 16);
      unsigned int hi = (unsigned int)f2bf(v.z * inv) | ((unsigned int)f2bf(v.w * inv) << 16);
      *(unsigned int*)(ap + j * 4)     = lo;
      *(unsigned int*)(ap + j * 4 + 2) = hi;
    }
  }
  __syncthreads();   // t2s + As ready

  // --- q_att: att[n] = t2 . ent[nbs[n]]
  {
    const float4* er = (const float4*)(ent + (size_t)nbs[n] * DD + seg * 64);
    const float4* ts = (const float4*)(t2s + seg * 64);
    float a = 0.f;
    #pragma unroll
    for (int j = 0; j < 16; ++j) {
      float4 v = er[j], t = ts[j];
      a += v.x * t.x + v.y * t.y + v.z * t.z + v.w * t.w;
    }
    a += __shfl_xor(a, 1);
    a += __shfl_xor(a, 2);
    if (seg == 0) att[n] = a;
  }

  // ---- GEMM: acc[i][j] = rowtile i, coltile (wv + 4*j) -> support s=j  (zero barriers)
  f32x4 acc[4][5];
  #pragma unroll
  for (int i = 0; i < 4; ++i)
    #pragma unroll
    for (int j = 0; j < 5; ++j) acc[i][j] = (f32x4){0.f, 0.f, 0.f, 0.f};

  const unsigned short* abase = As + fr * AP + kb * 8;
  const unsigned short* bbase = Bg + ((size_t)(wv * 16 + fr)) * DD + kb * 8;

  s16x8 bcur[5], bnxt[5], afr[4];
  #pragma unroll
  for (int j = 0; j < 5; ++j) bcur[j] = *(const s16x8*)(bbase + (size_t)j * 64 * DD);
  #pragma unroll
  for (int k = 0; k < 8; ++k) {
    #pragma unroll
    for (int i = 0; i < 4; ++i) afr[i] = *(const s16x8*)(abase + i * 16 * AP + k * 32);
    if (k < 7) {
      #pragma unroll
      for (int j = 0; j < 5; ++j)
        bnxt[j] = *(const s16x8*)(bbase + (size_t)j * 64 * DD + (k + 1) * 32);
    }
    #pragma unroll
    for (int i = 0; i < 4; ++i)
      #pragma unroll
      for (int j = 0; j < 5; ++j)
        acc[i][j] = __builtin_amdgcn_mfma_f32_16x16x32_bf16(afr[i], bcur[j], acc[i][j], 0, 0, 0);
    #pragma unroll
    for (int j = 0; j < 5; ++j) bcur[j] = bnxt[j];
  }

  // ---- col-reduce each 16x16 tile: D row = kb*4+reg, col = fr
  #pragma unroll
  for (int j = 0; j < 5; ++j) {
    #pragma unroll
    for (int i = 0; i < 4; ++i) {
      f32x4 mx = acc[i][j], mn = acc[i][j];
      #pragma unroll
      for (int off = 1; off < 16; off <<= 1) {
        #pragma unroll
        for (int r2 = 0; r2 < 4; ++r2) {
          mx[r2] = fmaxf(mx[r2], __shfl_xor(mx[r2], off));
          mn[r2] = fminf(mn[r2], __shfl_xor(mn[r2], off));
        }
      }
      if (fr == 0) {
        #pragma unroll
        for (int r2 = 0; r2 < 4; ++r2) {
          pmax[j][wv][i * 16 + kb * 4 + r2] = mx[r2];
          pmin[j][wv][i * 16 + kb * 4 + r2] = mn[r2];
        }
      }
    }
  }
  __syncthreads();

  float lmax = -3.0e38f;  // only tid 0's copy is used
  #pragma unroll 1
  for (int s5 = 0; s5 < NS; ++s5) {
    if (tid < NB) {
      float mx = fmaxf(fmaxf(pmax[s5][0][tid], pmax[s5][1][tid]),
                       fmaxf(pmax[s5][2][tid], pmax[s5][3][tid]));
      float mn = fminf(fminf(pmin[s5][0][tid], pmin[s5][1][tid]),
                       fminf(pmin[s5][2][tid], pmin[s5][3][tid]));
      float qa = att[tid];
      pol[tid] = (qa >= 0.f) ? qa * mx : qa * mn;
    }
    __syncthreads();
    if (tid < NK * 8) {
      int k = tid >> 3, np0 = tid & 7;
      double cur = 1.0;                       // replicate _kernel_mus in double
      if (k >= 1) {
        double bq = 1.0 / (double)(NK - 1);
        cur = 1.0 - bq * 0.5;
        for (int i2 = 1; i2 < k; ++i2) cur -= bq;
      }
      float mu = (float)cur;
      float sig = (k == 0) ? 0.001f : 0.1f;
      float s2 = sig * sig;
      float a = 0.f;
      for (int n2 = np0; n2 < NB; n2 += 8) {
        float dd = pol[n2] - mu;
        float x = dd * dd / s2 * 0.5f;
        a += msk[n2] * fmaxf(-x, LOGMIN);     // log(clip(exp(-x),1e-30)) == max(-x, ln 1e-30)
      }
      a += __shfl_xor(a, 1);
      a += __shfl_xor(a, 2);
      a += __shfl_xor(a, 4);
      if (np0 == 0) te[k] = a;
    }
    __syncthreads();
    float y = 0.f;
    if (tid < PROJ) {
      float h = d1b[tid];
      #pragma unroll
      for (int k = 0; k < NK; ++k) h += te[k] * d1w[tid * NK + k];
      y = h * d2w[tid];
    }
    #pragma unroll
    for (int off = 1; off < 64; off <<= 1) y += __shfl_xor(y, off);
    if ((tid & 63) == 0) wred[tid >> 6] = y;
    __syncthreads();
    if (tid == 0) {
      float logit = wred[0] + wred[1] + wred[2] + wred[3] + d2b[0];
      lmax = fmaxf(lmax, logit);  // max_s sigmoid(x) == sigmoid(max_s x)
    }
  }
  if (tid == 0) out[q] = 1.0f / (1.0f + expf(-lmax));
}

extern "C" void kernel_launch(void* const* d_in, const int* in_sizes, int n_in,
                              void* d_out, int out_size, void* d_ws, size_t ws_size,
                              hipStream_t stream) {
  const int* sh   = (const int*)d_in[0];
  const int* qh   = (const int*)d_in[1];
  const int* st   = (const int*)d_in[2];
  const int* qt   = (const int*)d_in[3];
  const int* ed   = (const int*)d_in[4];
  // d_in[5] = edge_nums (unused by the reference computation)
  const float* rel = (const float*)d_in[6];
  const float* ent = (const float*)d_in[7];
  const float* aw  = (const float*)d_in[8];
  const float* ab  = (const float*)d_in[9];
  const float* d1w = (const float*)d_in[10];
  const float* d1b = (const float*)d_in[11];
  const float* d2w = (const float*)d_in[12];
  const float* d2b = (const float*)d_in[13];
  float* out = (float*)d_out;

  float* ws = (float*)d_ws;
  float* wT = ws;                                        // 65,536 f
  unsigned short* Bb = (unsigned short*)(ws + 65536);    // 320*256 bf16 = 160 KB (16B-aligned)

  k_transpose<<<DD, DD, 0, stream>>>(aw, wT);
  k_support<<<NS, DD, 0, stream>>>(sh, st, ed, ent, rel, wT, ab, Bb);
  k_all<<<NQ, DD, 0, stream>>>(qh, qt, ed, ent, rel, wT, ab, Bb,
                               d1w, d1b, d2w, d2b, out);
}